// Round 8
// baseline (507.582 us; speedup 1.0000x reference)
//
#include <hip/hip_runtime.h>
#include <math.h>
#include <stdint.h>

#define BATCH 64
#define T 256
#define NF 64
#define H 128
#define H4 512                    // 4*H
#define HP1 129
#define WF_STRIDE (HP1 * H4)      // 66048 floats per feature
#define FEATS (NF * H + H)        // 8320
#define NTH2 512                  // 8 waves

#define RING_SLOT 32768           // one half-step (2 gates) of fp8 weights
// pack2: uint4 idx = (((f*8 + w)*2 + X)*4 + i)*64 + l   (4 MB)
#define PACK2_U4 (64 * 8 * 2 * 4 * 64)
#define PACK2_BYTES ((size_t)PACK2_U4 * 16u)
#define HDR2_BYTES  (64u * 512u * 16u)                   // 512 KB
#define WS_NEED ((size_t)HDR2_BYTES + PACK2_BYTES)       // 4.5 MB

typedef float vf2 __attribute__((ext_vector_type(2)));

__device__ __forceinline__ float sigmoidf_(float x) {
    return 1.0f / (1.0f + __expf(-x));
}

__device__ __forceinline__ float tanhf_(float x) {
    float ax = fabsf(x);
    float e = __expf(2.0f * ax);              // inf for large ax -> r = 1
    float r = 1.0f - 2.0f / (e + 1.0f);
    return copysignf(r, x);
}

// decode 2 fp8 bytes of a dword -> float2 (HI must be literal)
template<bool HI>
__device__ __forceinline__ vf2 dec2f(unsigned u) {
    return __builtin_amdgcn_cvt_pk_f32_fp8(u, HI);
}

__device__ __forceinline__ void dma16(const void* g, uint32_t lds_byte) {
    __builtin_amdgcn_global_load_lds(
        (const __attribute__((address_space(1))) void*)g,
        (__attribute__((address_space(3))) void*)(uintptr_t)lds_byte,
        16, 0, 0);
}

#define WAITV(N) do { asm volatile("s_waitcnt vmcnt(" #N ")" ::: "memory"); \
                      __builtin_amdgcn_sched_barrier(0); } while (0)
#define LGKM0()  do { asm volatile("s_waitcnt lgkmcnt(0)" ::: "memory"); \
                      __builtin_amdgcn_sched_barrier(0); } while (0)
#define BARRIER() do { asm volatile("s_waitcnt lgkmcnt(0)" ::: "memory"); \
                       __builtin_amdgcn_s_barrier(); \
                       asm volatile("" ::: "memory"); } while (0)

// ===== repack2: W_lin h-rows -> fp8 (x4096), per-(wave,lane) slice layout ====
// thread (w,l): h = w*16 + (l&15), ks = l>>4.
// uint4 (X,i): gate g = X*2 + (i>>1), ksub = i&1;
// byte b: k = ks*32 + ksub*16 + b, col = g*128 + h;
// val = fp8_e4m3(W_lin[f][1+k][col] * 4096)    (|W|*4096 <= 362 < 448)
__global__ __launch_bounds__(256)
void repack2_kernel(const float* __restrict__ W_lin, uint4* __restrict__ pack2) {
    const int lin = blockIdx.x * 256 + threadIdx.x;   // 0..262143
    const int l   = lin & 63;
    const int i   = (lin >> 6) & 3;
    const int Xv  = (lin >> 8) & 1;
    const int wv  = (lin >> 9) & 7;
    const int f   = lin >> 12;
    const int h   = wv * 16 + (l & 15);
    const int ks  = l >> 4;
    const int g   = Xv * 2 + (i >> 1);
    const int ksub = i & 1;
    const int col = g * 128 + h;
    const int k0  = ks * 32 + ksub * 16;
    const float* src = W_lin + (size_t)f * WF_STRIDE + (size_t)(1 + k0) * H4 + col;
    unsigned u[4];
    #pragma unroll
    for (int dw = 0; dw < 4; ++dw) {
        const float v0 = src[(4 * dw + 0) * H4] * 4096.0f;
        const float v1 = src[(4 * dw + 1) * H4] * 4096.0f;
        const float v2 = src[(4 * dw + 2) * H4] * 4096.0f;
        const float v3 = src[(4 * dw + 3) * H4] * 4096.0f;
        unsigned r = 0;
        r = __builtin_amdgcn_cvt_pk_fp8_f32(v0, v1, r, false);
        r = __builtin_amdgcn_cvt_pk_fp8_f32(v2, v3, r, true);
        u[dw] = r;
    }
    uint4 o; o.x = u[0]; o.y = u[1]; o.z = u[2]; o.w = u[3];
    pack2[lin] = o;
}

// hdr2[f*512 + tid] = uint4 of 8 fp16: {wx[g]=W_lin[f][0][g*128+h] g=0..3,
//                                       b[g]=b_lin[f][g*128+h]    g=0..3}
__global__ __launch_bounds__(256)
void hdr2_kernel(const float* __restrict__ W_lin, const float* __restrict__ b_lin,
                 uint4* __restrict__ hdr2) {
    const int lin = blockIdx.x * 256 + threadIdx.x;   // 0..32767
    const int t2 = lin & 511, f = lin >> 9;
    const int wv = t2 >> 6, l = t2 & 63;
    const int h  = wv * 16 + (l & 15);
    union { uint4 u; _Float16 hf[8]; } o;
    #pragma unroll
    for (int g = 0; g < 4; ++g) {
        o.hf[g]     = (_Float16)W_lin[(size_t)f * WF_STRIDE + g * 128 + h];
        o.hf[4 + g] = (_Float16)b_lin[f * H4 + g * 128 + h];
    }
    hdr2[lin] = o.u;
}

// ===== main scan: single-barrier step, in-wave gate path, fp8 DMA ring ======
// Thread = (h = w*16 + (l&15), ks = l>>4): all 4 gates of h over 32 k's.
// K-reduce via shfl_xor(16/32) inside the wave; gates computed redundantly by
// all 4 dup lanes (c_t/acc/cnt in regs, bit-identical). ONE s_barrier/step
// (for s_inp). Weights via R7's DMA ring, per-wave vmcnt(9) accounting.
__global__ __launch_bounds__(NTH2)
void lstm_scan_fp8_w1(const float* __restrict__ X,
                      const int* __restrict__ lengths,
                      const float* __restrict__ W_dec,
                      const float* __restrict__ b_dec,
                      const float* __restrict__ W_out,
                      const float* __restrict__ b_out,
                      const uint4* __restrict__ pack2,
                      const uint4* __restrict__ hdr2,
                      float* __restrict__ out)
{
    __shared__ __align__(16) char s_wb[3 * RING_SLOT];  // 96 KB weight ring
    __shared__ __align__(16) char s_hd[2 * 8192];       // hdr staging (dbuf)
    __shared__ float s_ht[NF * H];                      // 32 KB h table
    __shared__ float s_inp[H];                          // decayed hidden (f32)
    __shared__ float s_X[4 * T];
    __shared__ float s_wdec[NF];
    __shared__ float s_bdec[NF];
    __shared__ float s_cfin[H];
    __shared__ float s_red[16];

    const int tid = threadIdx.x;
    const int b   = blockIdx.x;
    const int w   = tid >> 6;
    const int l   = tid & 63;
    const int h   = w * 16 + (l & 15);
    const int ks  = l >> 4;

    const float* Xb = X + b * 4 * T;
    const int len = lengths[b];

    for (int i = tid; i < NF * H; i += NTH2) s_ht[i] = 0.0f;
    for (int i = tid; i < 4 * T; i += NTH2) s_X[i] = Xb[i];
    if (tid < NF) { s_wdec[tid] = W_dec[tid]; s_bdec[tid] = b_dec[tid]; }
    if (tid < H) s_inp[tid] = 0.0f;
    __syncthreads();

    const uint32_t wb0 = (uint32_t)(uintptr_t)s_wb;
    const uint32_t hd0 = (uint32_t)(uintptr_t)s_hd;
    const uint32_t wbase  = __builtin_amdgcn_readfirstlane(wb0 + (uint32_t)w * 4096u);
    const uint32_t hdbase = __builtin_amdgcn_readfirstlane(hd0 + (uint32_t)w * 1024u);

    float c_t = 0.0f, accv = 0.0f, cntv = 0.0f;

    #define ISSUE_W4(mf, Xv, slot) do {                                          \
        const uint4* gp = pack2 + ((((size_t)(mf) * 8 + w) * 2 + (Xv)) * 4) * 64 + l; \
        const uint32_t dst = wbase + (uint32_t)(slot) * RING_SLOT;               \
        dma16(gp,       dst);                                                    \
        dma16(gp + 64,  dst + 1024u);                                            \
        dma16(gp + 128, dst + 2048u);                                            \
        dma16(gp + 192, dst + 3072u);                                            \
    } while (0)

    #define ISSUE_HDR(jj) do {                                                   \
        const int ss = ((jj) < T) ? (jj) : (T - 1);                              \
        const int mf = (int)s_X[T + ss];                                         \
        const uint4* gh = hdr2 + (size_t)mf * 512 + (w * 64 + l);                \
        dma16(gh, hdbase + (((jj) & 1) ? 8192u : 0u));                           \
    } while (0)

    // one weight uint4 (16 fp8, k = ksub*16 + b) vs input pairs iv[ksub*8 + p]
    #define DOTQ(Wq, G, KS) do {                                                 \
        const int pb = (KS) * 8;                                                 \
        vf2 d;                                                                   \
        d = dec2f<false>((Wq).x); acc[G] += d * iv[pb + 0];                      \
        d = dec2f<true >((Wq).x); acc[G] += d * iv[pb + 1];                      \
        d = dec2f<false>((Wq).y); acc[G] += d * iv[pb + 2];                      \
        d = dec2f<true >((Wq).y); acc[G] += d * iv[pb + 3];                      \
        d = dec2f<false>((Wq).z); acc[G] += d * iv[pb + 4];                      \
        d = dec2f<true >((Wq).z); acc[G] += d * iv[pb + 5];                      \
        d = dec2f<false>((Wq).w); acc[G] += d * iv[pb + 6];                      \
        d = dec2f<true >((Wq).w); acc[G] += d * iv[pb + 7];                      \
    } while (0)

    // asm ds_read: ring is DMA-written; compiler sees no stores -> must not CSE
    #define HALFX(Xv, slot) do {                                                 \
        uint4 q0, q1, q2, q3;                                                    \
        const uint32_t ra = wb0 + (uint32_t)(slot) * RING_SLOT                   \
                          + (uint32_t)w * 4096u + (uint32_t)l * 16u;             \
        asm volatile("ds_read_b128 %0, %4 offset:0\n\t"                          \
                     "ds_read_b128 %1, %4 offset:1024\n\t"                       \
                     "ds_read_b128 %2, %4 offset:2048\n\t"                       \
                     "ds_read_b128 %3, %4 offset:3072"                           \
                     : "=&v"(q0), "=&v"(q1), "=&v"(q2), "=&v"(q3)                \
                     : "v"(ra) : "memory");                                      \
        asm volatile("s_waitcnt lgkmcnt(0)" ::: "memory");                       \
        __builtin_amdgcn_sched_barrier(0);                                       \
        DOTQ(q0, (Xv) * 2 + 0, 0);                                               \
        DOTQ(q1, (Xv) * 2 + 0, 1);                                               \
        DOTQ(q2, (Xv) * 2 + 1, 0);                                               \
        DOTQ(q3, (Xv) * 2 + 1, 1);                                               \
    } while (0)

    // prologue: stage step 0 -> 9 outstanding [Wh0 x4, hdr0, Wh1 x4]
    {
        const int m0 = (int)s_X[T];
        ISSUE_W4(m0, 0, 0);
        ISSUE_HDR(0);
        ISSUE_W4(m0, 1, 1);
    }

    int r0 = 0;
    for (int j = 0; j < len; ++j) {
        const int   mj  = (int)s_X[T + j];
        const float xj  = s_X[2 * T + j];
        const int   jn  = (j + 1 < T) ? (j + 1) : (T - 1);
        const int   mjn = (int)s_X[T + jn];
        int r1 = r0 + 1; if (r1 >= 3) r1 -= 3;
        int r2 = r0 + 2; if (r2 >= 3) r2 -= 3;

        // stage next step's first half + hdr (slot r2 free since step j-1)
        ISSUE_W4(mjn, 0, r2);
        ISSUE_HDR(j + 1);

        // input slice -> registers (32 f32 = 16 pairs)
        vf2 iv[16];
        {
            const float4* ip = (const float4*)(s_inp + ks * 32);
            #pragma unroll
            for (int q = 0; q < 8; ++q) {
                const float4 t = ip[q];
                iv[2 * q][0] = t.x;  iv[2 * q][1] = t.y;
                iv[2 * q + 1][0] = t.z; iv[2 * q + 1][1] = t.w;
            }
        }
        vf2 acc[4];
        #pragma unroll
        for (int g = 0; g < 4; ++g) { acc[g][0] = 0.0f; acc[g][1] = 0.0f; }

        WAITV(9);                              // W(j,h0) + hdr(j) landed
        HALFX(0, r0);                          // gates 0,1

        uint4 hb;
        {
            const uint32_t ha = hd0 + ((j & 1) ? 8192u : 0u)
                              + (uint32_t)w * 1024u + (uint32_t)l * 16u;
            asm volatile("ds_read_b128 %0, %1" : "=&v"(hb) : "v"(ha) : "memory");
        }
        LGKM0();                               // r0 reads + hb retired
        ISSUE_W4(mjn, 1, r0);                  // overwrite r0 with (j+1,h1)
        WAITV(9);                              // W(j,h1) landed
        HALFX(1, r1);                          // gates 2,3

        // in-wave K reduction + gate math (all lanes, 4x redundant per h)
        union { uint4 u; _Float16 hf[8]; } hu; hu.u = hb;
        float gate[4];
        #pragma unroll
        for (int g = 0; g < 4; ++g) {
            float s = acc[g][0] + acc[g][1];
            s += __shfl_xor(s, 16, 64);
            s += __shfl_xor(s, 32, 64);
            gate[g] = fmaf(s, 1.0f / 4096.0f,
                           fmaf(xj, (float)hu.hf[g], (float)hu.hf[4 + g]));
        }
        const float c_cand = sigmoidf_(gate[1]) * c_t + sigmoidf_(gate[0]) * tanhf_(gate[3]);
        const float h_row  = sigmoidf_(gate[2]) * tanhf_(c_cand);
        accv += c_cand;
        cntv += 1.0f;
        const float tj = s_X[j];
        const float tn = (j < T - 1) ? s_X[j + 1] : (tj + 1.0f);
        const bool boundary = (j == len - 1) || (tn != tj);
        if (boundary) { c_t = accv / fmaxf(cntv, 1.0f); accv = 0.0f; cntv = 0.0f; }
        if ((l & 48) == 0) {                   // ks==0 lane writes its h
            s_ht[mj * H + h] = h_row;
            const float dn  = s_X[3 * T + jn];
            const float dmn = fmaf(s_wdec[mjn], dn, s_bdec[mjn]);
            const float den = __expf(-fmaxf(0.0f, dmn));
            const float hv  = (mjn == mj) ? h_row : s_ht[mjn * H + h];
            s_inp[h] = den * hv;
        }
        BARRIER();                             // s_inp/s_ht ready (vmcnt alive)
        r0 = r2;
    }
    #undef HALFX
    #undef DOTQ
    #undef ISSUE_HDR
    #undef ISSUE_W4

    asm volatile("s_waitcnt vmcnt(0) lgkmcnt(0)" ::: "memory");
    __syncthreads();

    // ---- epilogue ----
    if ((l & 48) == 0) s_cfin[h] = c_t;
    __syncthreads();

    float z0 = 0.0f, z1 = 0.0f;
    for (int i = tid; i < FEATS; i += NTH2) {
        const float f = (i < H) ? s_cfin[i] : s_ht[i - H];
        const float2 wo = *(const float2*)(W_out + 2 * i);
        z0 = fmaf(f, wo.x, z0);
        z1 = fmaf(f, wo.y, z1);
    }
    #pragma unroll
    for (int off = 32; off > 0; off >>= 1) {
        z0 += __shfl_down(z0, off, 64);
        z1 += __shfl_down(z1, off, 64);
    }
    if (l == 0) { s_red[2 * w] = z0; s_red[2 * w + 1] = z1; }
    __syncthreads();
    if (tid == 0) {
        float a0 = b_out[0], a1 = b_out[1];
        #pragma unroll
        for (int q = 0; q < 8; ++q) { a0 += s_red[2 * q]; a1 += s_red[2 * q + 1]; }
        const float mx = fmaxf(a0, a1);
        const float e0 = __expf(a0 - mx), e1 = __expf(a1 - mx);
        const float inv = 1.0f / (e0 + e1);
        out[2 * b]     = e0 * inv;
        out[2 * b + 1] = e1 * inv;
    }
}

// ---------------- fp32 fallback (no-workspace path) ----------------
#define NTHREADS 512
__global__ __launch_bounds__(NTHREADS)
void lstm_scan_kernel(const float* __restrict__ X,
                      const int* __restrict__ lengths,
                      const float* __restrict__ W_lin,
                      const float* __restrict__ b_lin,
                      const float* __restrict__ W_dec,
                      const float* __restrict__ b_dec,
                      const float* __restrict__ W_out,
                      const float* __restrict__ b_out,
                      float* __restrict__ out)
{
    __shared__ float s_feats[FEATS];
    __shared__ float s_inp[H];
    __shared__ float s_part[4][H4];
    __shared__ float s_X[4 * T];
    __shared__ float s_wdec[NF];
    __shared__ float s_bdec[NF];
    __shared__ float s_red[16];

    float* s_ct = s_feats;
    float* s_ht = s_feats + H;

    const int tid = threadIdx.x;
    const int b   = blockIdx.x;
    const int g4  = tid & 127;
    const int kq  = tid >> 7;

    const float* Xb = X + b * 4 * T;
    const int len = lengths[b];

    for (int i = tid; i < NF * H; i += NTHREADS) s_ht[i] = 0.0f;
    for (int i = tid; i < 4 * T; i += NTHREADS) s_X[i] = Xb[i];
    if (tid < NF) { s_wdec[tid] = W_dec[tid]; s_bdec[tid] = b_dec[tid]; }
    __syncthreads();

    float c_t = 0.0f, acc = 0.0f, cnt = 0.0f;

    for (int j = 0; j < len; ++j) {
        const int   mj = (int)s_X[T + j];
        const float xj = s_X[2 * T + j];
        const float* Wf = W_lin + mj * WF_STRIDE;

        float bl0, bl1, bl2, bl3;
        if (tid < H) {
            const float dj    = s_X[3 * T + j];
            const float dm    = fmaf(s_wdec[mj], dj, s_bdec[mj]);
            const float decay = __expf(-fmaxf(0.0f, dm));
            s_inp[tid] = decay * s_ht[mj * H + tid];
            const int m4 = mj * H4;
            bl0 = b_lin[m4 + tid];
            bl1 = b_lin[m4 + H + tid];
            bl2 = b_lin[m4 + 2 * H + tid];
            bl3 = b_lin[m4 + 3 * H + tid];
        }
        __syncthreads();

        float4 a4 = make_float4(0.0f, 0.0f, 0.0f, 0.0f);
        {
            const float*  wr  = Wf + (1 + kq * 32) * H4 + 4 * g4;
            const float4* ivp = (const float4*)(s_inp + kq * 32);
            #pragma unroll
            for (int cc = 0; cc < 8; ++cc) {
                const float4 v = ivp[cc];
                const float* wrc = wr + (4 * cc) * H4;
                const float4 w0 = *(const float4*)(wrc);
                const float4 w1 = *(const float4*)(wrc + H4);
                const float4 w2 = *(const float4*)(wrc + 2 * H4);
                const float4 w3 = *(const float4*)(wrc + 3 * H4);
                a4.x = fmaf(v.x, w0.x, a4.x); a4.y = fmaf(v.x, w0.y, a4.y);
                a4.z = fmaf(v.x, w0.z, a4.z); a4.w = fmaf(v.x, w0.w, a4.w);
                a4.x = fmaf(v.y, w1.x, a4.x); a4.y = fmaf(v.y, w1.y, a4.y);
                a4.z = fmaf(v.y, w1.z, a4.z); a4.w = fmaf(v.y, w1.w, a4.w);
                a4.x = fmaf(v.z, w2.x, a4.x); a4.y = fmaf(v.z, w2.y, a4.y);
                a4.z = fmaf(v.z, w2.z, a4.z); a4.w = fmaf(v.z, w2.w, a4.w);
                a4.x = fmaf(v.w, w3.x, a4.x); a4.y = fmaf(v.w, w3.y, a4.y);
                a4.z = fmaf(v.w, w3.z, a4.z); a4.w = fmaf(v.w, w3.w, a4.w);
            }
        }
        if (kq == 0) {
            const float4 wv = *(const float4*)(Wf + 4 * g4);
            a4.x = fmaf(xj, wv.x, a4.x); a4.y = fmaf(xj, wv.y, a4.y);
            a4.z = fmaf(xj, wv.z, a4.z); a4.w = fmaf(xj, wv.w, a4.w);
        }
        *(float4*)(&s_part[kq][4 * g4]) = a4;
        __syncthreads();

        if (tid < H) {
            const int h = tid;
            const float gi = s_part[0][h]         + s_part[1][h]         + s_part[2][h]         + s_part[3][h]         + bl0;
            const float gf = s_part[0][H + h]     + s_part[1][H + h]     + s_part[2][H + h]     + s_part[3][H + h]     + bl1;
            const float go = s_part[0][2*H + h]   + s_part[1][2*H + h]   + s_part[2][2*H + h]   + s_part[3][2*H + h]   + bl2;
            const float gc = s_part[0][3*H + h]   + s_part[1][3*H + h]   + s_part[2][3*H + h]   + s_part[3][3*H + h]   + bl3;

            const float c_cand = sigmoidf_(gf) * c_t + sigmoidf_(gi) * tanhf_(gc);
            const float h_row  = sigmoidf_(go) * tanhf_(c_cand);
            s_ht[mj * H + h] = h_row;
            acc += c_cand;
            cnt += 1.0f;

            const float tj = s_X[j];
            const float tn = (j < T - 1) ? s_X[j + 1] : (tj + 1.0f);
            const bool boundary = (j == len - 1) || (tn != tj);
            if (boundary) { c_t = acc / fmaxf(cnt, 1.0f); acc = 0.0f; cnt = 0.0f; }
        }
        __syncthreads();
    }

    if (tid < H) s_ct[tid] = c_t;
    __syncthreads();

    float z0 = 0.0f, z1 = 0.0f;
    for (int i = tid; i < FEATS; i += NTHREADS) {
        const float f = s_feats[i];
        const float2 wv = *(const float2*)(W_out + 2 * i);
        z0 = fmaf(f, wv.x, z0);
        z1 = fmaf(f, wv.y, z1);
    }
    #pragma unroll
    for (int off = 32; off > 0; off >>= 1) {
        z0 += __shfl_down(z0, off, 64);
        z1 += __shfl_down(z1, off, 64);
    }
    const int wave = tid >> 6, lane = tid & 63;
    if (lane == 0) { s_red[2 * wave] = z0; s_red[2 * wave + 1] = z1; }
    __syncthreads();
    if (tid == 0) {
        float a0 = b_out[0], a1 = b_out[1];
        #pragma unroll
        for (int q = 0; q < 8; ++q) { a0 += s_red[2 * q]; a1 += s_red[2 * q + 1]; }
        const float mx = fmaxf(a0, a1);
        const float e0 = __expf(a0 - mx), e1 = __expf(a1 - mx);
        const float inv = 1.0f / (e0 + e1);
        out[2 * b]     = e0 * inv;
        out[2 * b + 1] = e1 * inv;
    }
}

extern "C" void kernel_launch(void* const* d_in, const int* in_sizes, int n_in,
                              void* d_out, int out_size, void* d_ws, size_t ws_size,
                              hipStream_t stream) {
    const float* X      = (const float*)d_in[0];
    const int*   lens   = (const int*)d_in[1];
    const float* W_lin  = (const float*)d_in[2];
    const float* b_lin  = (const float*)d_in[3];
    const float* W_dec  = (const float*)d_in[4];
    const float* b_dec  = (const float*)d_in[5];
    const float* W_out  = (const float*)d_in[6];
    const float* b_out  = (const float*)d_in[7];
    float* out = (float*)d_out;

    if (ws_size >= WS_NEED) {
        uint4* hdr2 = (uint4*)d_ws;
        uint4* pack2 = (uint4*)((char*)d_ws + HDR2_BYTES);
        hipLaunchKernelGGL(hdr2_kernel, dim3(128), dim3(256), 0, stream,
                           W_lin, b_lin, hdr2);
        hipLaunchKernelGGL(repack2_kernel, dim3(PACK2_U4 / 256), dim3(256), 0, stream,
                           W_lin, pack2);
        hipLaunchKernelGGL(lstm_scan_fp8_w1, dim3(BATCH), dim3(NTH2), 0, stream,
                           X, lens, W_dec, b_dec, W_out, b_out, pack2, hdr2, out);
    } else {
        hipLaunchKernelGGL(lstm_scan_kernel, dim3(BATCH), dim3(NTHREADS), 0, stream,
                           X, lens, W_lin, b_lin, W_dec, b_dec, W_out, b_out, out);
    }
}